// Round 4
// baseline (326.316 us; speedup 1.0000x reference)
//
#include <hip/hip_runtime.h>

// SobelLoss: loss = valid * (|gx| + |gy|), d = pred - tgt, separable Sobel:
//   v1[w] = d[h-1,w] + 2 d[h,w] + d[h+1,w];  gx = v1[w+1] - v1[w-1]
//   v2[w] = d[h+1,w] - d[h-1,w];             gy = v2[w-1] + 2 v2[w] + v2[w+1]
// valid = AND of mask 3x3 (zero-padded -> borders 0).
// Shapes: 12 images x 512 x 512 x 8 fp32, F innermost.
//
// R4: wave-autonomous, ZERO barriers / ZERO LDS arrays.
//   - wave = 32-px strip x 32-row segment; 2 lanes per px (q = lane&1),
//     lane l loads base + l*16B -> perfectly contiguous 1KB per b128 load.
//   - 3-row register ring of d + packed mask nibble; 2-row-deep raw prefetch
//     (rows h+2, h+3 in flight) -> ~6 outstanding b128/wave.
//   - horizontal neighbor exchange via __shfl(lane +/- 2) (DS pipe, no sync).
//   - outputs px p in [1,31) of the 32 staged (edge lanes are halo-only).
// R1-R3 were all latency-bound (HBM <= 31%, VALU <= 11%): R2's 9-pt LDS
// reread chain, R3's per-row barrier + serialized wave-0 halo loads.

constexpr int H = 512, W = 512, F = 8;
constexpr int IMAGES = 12;               // B*T
constexpr int SEG_H = 32;                // rows per wave
constexpr int SEGS = H / SEG_H;          // 16
constexpr int STRIPS = 18;               // 18 * 30 output px >= 512
constexpr int ROWE = W * F;              // elements per image row
constexpr size_t IMG_ELEMS = (size_t)H * W * F;

__device__ __forceinline__ float4 sub4(float4 a, float4 b) {
    return make_float4(a.x - b.x, a.y - b.y, a.z - b.z, a.w - b.w);
}

__device__ __forceinline__ float4 shfl4(float4 v, int src) {
    float4 r;
    r.x = __shfl(v.x, src, 64);
    r.y = __shfl(v.y, src, 64);
    r.z = __shfl(v.z, src, 64);
    r.w = __shfl(v.w, src, 64);
    return r;
}

struct RowRaw { float4 p, t; int4 m; };

__device__ __forceinline__ RowRaw load_row(const float* __restrict__ pred,
                                           const float* __restrict__ tgt,
                                           const int*   __restrict__ mask,
                                           size_t colbase, int h) {
    const int hc = min(max(h, 0), H - 1);
    const size_t off = colbase + (size_t)hc * ROWE;
    RowRaw r;
    r.p = *(const float4*)(pred + off);
    r.t = *(const float4*)(tgt + off);
    r.m = *(const int4*)(mask + off);
    return r;
}

__device__ __forceinline__ void fold(const RowRaw& r, int hval, bool gpin,
                                     float4& d, unsigned& mv) {
    d = sub4(r.p, r.t);
    const unsigned pk = (unsigned)(r.m.x | (r.m.y << 1) | (r.m.z << 2) | (r.m.w << 3));
    mv = (hval >= 0 && hval < H && gpin) ? pk : 0u;
}

__global__ __launch_bounds__(256) void sobel_loss_kernel(
    const float* __restrict__ pred,
    const float* __restrict__ tgt,
    const int*   __restrict__ mask,
    float*       __restrict__ out)
{
    const int lane = threadIdx.x & 63;
    const int wid  = (blockIdx.x << 2) + (threadIdx.x >> 6);
    const int seg  = wid & (SEGS - 1);           // fastest -> vertical L2 locality
    const int t2   = wid >> 4;
    const int strip = t2 % STRIPS;
    const int img   = t2 / STRIPS;

    const int h0 = seg << 5;                     // even
    const int ws = strip * 30;
    const int p  = lane >> 1;                    // staged px index 0..31
    const int qq = lane & 1;
    const int gp = ws - 1 + p;                   // staged global px (-1..541)
    const bool gpin = (gp >= 0) & (gp < W);
    const int gpc = min(max(gp, 0), W - 1);
    const size_t ibase = (size_t)img * IMG_ELEMS;
    const size_t colbase = ibase + (size_t)gpc * F + qq * 4;

    // Register ring: rows h-1, h, h+1.
    float4 dm1, d0c, dp1;
    unsigned mm1, m0c, mp1;
    {
        RowRaw r = load_row(pred, tgt, mask, colbase, h0 - 1);
        fold(r, h0 - 1, gpin, dm1, mm1);
        r = load_row(pred, tgt, mask, colbase, h0);
        fold(r, h0, gpin, d0c, m0c);
        r = load_row(pred, tgt, mask, colbase, h0 + 1);
        fold(r, h0 + 1, gpin, dp1, mp1);
    }
    // Two raw prefetch stages (rows h+2, h+3 in flight).
    RowRaw stageA = load_row(pred, tgt, mask, colbase, h0 + 2);
    RowRaw stageB = load_row(pred, tgt, mask, colbase, h0 + 3);

    const bool do_store = (p >= 1) & (p < 31) & (gp < W);
    const int lm2 = lane - 2, lp2 = lane + 2;    // wrap for edge lanes: unused
    const int hmax = h0 + SEG_H;                 // last row ever needed

    float* const outcol = out + ibase + (size_t)gp * F + qq * 4;

    auto step = [&](int h, RowRaw& stage) {
        // Vertical pass (registers only).
        const float4 v1 = make_float4(fmaf(2.f, d0c.x, dm1.x) + dp1.x,
                                      fmaf(2.f, d0c.y, dm1.y) + dp1.y,
                                      fmaf(2.f, d0c.z, dm1.z) + dp1.z,
                                      fmaf(2.f, d0c.w, dm1.w) + dp1.w);
        const float4 v2 = sub4(dp1, dm1);
        const unsigned mvv = mm1 & m0c & mp1;

        // Horizontal pass via cross-lane shuffle (neighbor px = lane +/- 2).
        const float4 v1l = shfl4(v1, lm2), v1r = shfl4(v1, lp2);
        const float4 v2l = shfl4(v2, lm2), v2r = shfl4(v2, lp2);
        const unsigned ml = (unsigned)__shfl((int)mvv, lm2, 64);
        const unsigned mr = (unsigned)__shfl((int)mvv, lp2, 64);
        const unsigned valid = mvv & ml & mr;

        float4 res;
        res.x = (valid & 1u) ? fabsf(v1r.x - v1l.x) + fabsf(fmaf(2.f, v2.x, v2l.x) + v2r.x) : 0.f;
        res.y = (valid & 2u) ? fabsf(v1r.y - v1l.y) + fabsf(fmaf(2.f, v2.y, v2l.y) + v2r.y) : 0.f;
        res.z = (valid & 4u) ? fabsf(v1r.z - v1l.z) + fabsf(fmaf(2.f, v2.z, v2l.z) + v2r.z) : 0.f;
        res.w = (valid & 8u) ? fabsf(v1r.w - v1l.w) + fabsf(fmaf(2.f, v2.w, v2l.w) + v2r.w) : 0.f;

        if (do_store)
            *(float4*)(outcol + (size_t)h * ROWE) = res;

        // Rotate ring; consume stage (row h+2, issued 2 iterations ago);
        // refill stage with row h+4 (clamped re-load of hmax at tail is L1-hot).
        dm1 = d0c; mm1 = m0c;
        d0c = dp1; m0c = mp1;
        fold(stage, h + 2, gpin, dp1, mp1);
        stage = load_row(pred, tgt, mask, colbase, min(h + 4, hmax));
    };

    for (int h = h0; h < hmax; h += 2) {
        step(h,     stageA);
        step(h + 1, stageB);
    }
}

extern "C" void kernel_launch(void* const* d_in, const int* in_sizes, int n_in,
                              void* d_out, int out_size, void* d_ws, size_t ws_size,
                              hipStream_t stream) {
    const float* pred = (const float*)d_in[0];
    const float* tgt  = (const float*)d_in[1];
    const int*   mask = (const int*)d_in[2];
    float*       out  = (float*)d_out;

    // 12 img * 18 strips * 16 segs = 3456 waves = 864 blocks of 4 waves.
    const int blocks = IMAGES * STRIPS * SEGS / 4;
    sobel_loss_kernel<<<blocks, 256, 0, stream>>>(pred, tgt, mask, out);
}

// Round 5
// 307.606 us; speedup vs baseline: 1.0608x; 1.0608x over previous
//
#include <hip/hip_runtime.h>

// SobelLoss: loss = valid * (|gx| + |gy|), d = pred - tgt, separable Sobel:
//   v1[w] = d[h-1,w] + 2 d[h,w] + d[h+1,w];  gx = v1[w+1] - v1[w-1]
//   v2[w] = d[h+1,w] - d[h-1,w];             gy = v2[w-1] + 2 v2[w] + v2[w+1]
// valid = AND of mask 3x3 (zero-padded -> borders 0).
// Shapes: 12 images x 512 x 512 x 8 fp32, F innermost.
//
// R5: R4's wave-autonomous sliding window (0 barriers, 0 LDS, shfl neighbor
// exchange) with 4x the waves: SEG_H 32 -> 8 rows/wave.
//   R4 post-mortem: dur tracks resident waves across ALL rounds; R4 was
//   grid-limited to 13.5 waves/CU (Occupancy 30%) -> latency not covered.
//   13824 waves = 54/CU oversubscribed; VGPR=36 keeps 8 waves/SIMD, so
//   32 resident/CU * 6KB outstanding = 192KB/CU in flight (~49 MB total,
//   2.4x the latency-BW product of 22 MB).
// Within a block, the 4 waves are 4 consecutive segments of one strip ->
// vertical halo rows shared through the same CU's L1/L2.

constexpr int H = 512, W = 512, F = 8;
constexpr int IMAGES = 12;               // B*T
constexpr int SEG_H = 8;                 // rows per wave
constexpr int SEGS = H / SEG_H;          // 64
constexpr int STRIPS = 18;               // 18 * 30 output px >= 512
constexpr int ROWE = W * F;              // elements per image row
constexpr size_t IMG_ELEMS = (size_t)H * W * F;

__device__ __forceinline__ float4 sub4(float4 a, float4 b) {
    return make_float4(a.x - b.x, a.y - b.y, a.z - b.z, a.w - b.w);
}

__device__ __forceinline__ float4 shfl4(float4 v, int src) {
    float4 r;
    r.x = __shfl(v.x, src, 64);
    r.y = __shfl(v.y, src, 64);
    r.z = __shfl(v.z, src, 64);
    r.w = __shfl(v.w, src, 64);
    return r;
}

struct RowRaw { float4 p, t; int4 m; };

__device__ __forceinline__ RowRaw load_row(const float* __restrict__ pred,
                                           const float* __restrict__ tgt,
                                           const int*   __restrict__ mask,
                                           size_t colbase, int h) {
    const int hc = min(max(h, 0), H - 1);
    const size_t off = colbase + (size_t)hc * ROWE;
    RowRaw r;
    r.p = *(const float4*)(pred + off);
    r.t = *(const float4*)(tgt + off);
    r.m = *(const int4*)(mask + off);
    return r;
}

__device__ __forceinline__ void fold(const RowRaw& r, int hval, bool gpin,
                                     float4& d, unsigned& mv) {
    d = sub4(r.p, r.t);
    const unsigned pk = (unsigned)(r.m.x | (r.m.y << 1) | (r.m.z << 2) | (r.m.w << 3));
    mv = (hval >= 0 && hval < H && gpin) ? pk : 0u;
}

__global__ __launch_bounds__(256) void sobel_loss_kernel(
    const float* __restrict__ pred,
    const float* __restrict__ tgt,
    const int*   __restrict__ mask,
    float*       __restrict__ out)
{
    const int lane = threadIdx.x & 63;
    const int wid  = (blockIdx.x << 2) + (threadIdx.x >> 6);
    const int seg  = wid & (SEGS - 1);           // fastest: block = 4 consecutive segs
    const int t2   = wid >> 6;
    const int strip = t2 % STRIPS;
    const int img   = t2 / STRIPS;

    const int h0 = seg * SEG_H;
    const int ws = strip * 30;
    const int p  = lane >> 1;                    // staged px index 0..31
    const int qq = lane & 1;
    const int gp = ws - 1 + p;                   // staged global px (-1..541)
    const bool gpin = (gp >= 0) & (gp < W);
    const int gpc = min(max(gp, 0), W - 1);
    const size_t ibase = (size_t)img * IMG_ELEMS;
    const size_t colbase = ibase + (size_t)gpc * F + qq * 4;

    // Register ring: rows h-1, h, h+1.
    float4 dm1, d0c, dp1;
    unsigned mm1, m0c, mp1;
    {
        RowRaw r = load_row(pred, tgt, mask, colbase, h0 - 1);
        fold(r, h0 - 1, gpin, dm1, mm1);
        r = load_row(pred, tgt, mask, colbase, h0);
        fold(r, h0, gpin, d0c, m0c);
        r = load_row(pred, tgt, mask, colbase, h0 + 1);
        fold(r, h0 + 1, gpin, dp1, mp1);
    }
    // Two raw prefetch stages (rows h+2, h+3 in flight).
    RowRaw stageA = load_row(pred, tgt, mask, colbase, h0 + 2);
    RowRaw stageB = load_row(pred, tgt, mask, colbase, h0 + 3);

    const bool do_store = (p >= 1) & (p < 31) & (gp < W);
    const int lm2 = lane - 2, lp2 = lane + 2;    // edge-lane wrap values unused
    const int hmax = h0 + SEG_H;

    float* const outcol = out + ibase + (size_t)gp * F + qq * 4;

    auto step = [&](int h, RowRaw& stage) {
        // Vertical pass (registers only).
        const float4 v1 = make_float4(fmaf(2.f, d0c.x, dm1.x) + dp1.x,
                                      fmaf(2.f, d0c.y, dm1.y) + dp1.y,
                                      fmaf(2.f, d0c.z, dm1.z) + dp1.z,
                                      fmaf(2.f, d0c.w, dm1.w) + dp1.w);
        const float4 v2 = sub4(dp1, dm1);
        const unsigned mvv = mm1 & m0c & mp1;

        // Horizontal pass via cross-lane shuffle (neighbor px = lane +/- 2).
        const float4 v1l = shfl4(v1, lm2), v1r = shfl4(v1, lp2);
        const float4 v2l = shfl4(v2, lm2), v2r = shfl4(v2, lp2);
        const unsigned ml = (unsigned)__shfl((int)mvv, lm2, 64);
        const unsigned mr = (unsigned)__shfl((int)mvv, lp2, 64);
        const unsigned valid = mvv & ml & mr;

        float4 res;
        res.x = (valid & 1u) ? fabsf(v1r.x - v1l.x) + fabsf(fmaf(2.f, v2.x, v2l.x) + v2r.x) : 0.f;
        res.y = (valid & 2u) ? fabsf(v1r.y - v1l.y) + fabsf(fmaf(2.f, v2.y, v2l.y) + v2r.y) : 0.f;
        res.z = (valid & 4u) ? fabsf(v1r.z - v1l.z) + fabsf(fmaf(2.f, v2.z, v2l.z) + v2r.z) : 0.f;
        res.w = (valid & 8u) ? fabsf(v1r.w - v1l.w) + fabsf(fmaf(2.f, v2.w, v2l.w) + v2r.w) : 0.f;

        if (do_store)
            *(float4*)(outcol + (size_t)h * ROWE) = res;

        // Rotate ring; consume stage (row h+2, issued 2 steps ago);
        // refill with row h+4 (clamped tail re-load is L1-hot and unused).
        dm1 = d0c; mm1 = m0c;
        d0c = dp1; m0c = mp1;
        fold(stage, h + 2, gpin, dp1, mp1);
        stage = load_row(pred, tgt, mask, colbase, min(h + 4, hmax));
    };

#pragma unroll
    for (int h = h0; h < hmax; h += 2) {
        step(h,     stageA);
        step(h + 1, stageB);
    }
}

extern "C" void kernel_launch(void* const* d_in, const int* in_sizes, int n_in,
                              void* d_out, int out_size, void* d_ws, size_t ws_size,
                              hipStream_t stream) {
    const float* pred = (const float*)d_in[0];
    const float* tgt  = (const float*)d_in[1];
    const int*   mask = (const int*)d_in[2];
    float*       out  = (float*)d_out;

    // 12 img * 18 strips * 64 segs = 13824 waves = 3456 blocks of 4 waves.
    const int blocks = IMAGES * STRIPS * SEGS / 4;
    sobel_loss_kernel<<<blocks, 256, 0, stream>>>(pred, tgt, mask, out);
}